// Round 1
// baseline (127.583 us; speedup 1.0000x reference)
//
#include <hip/hip_runtime.h>
#include <math.h>

// Fused SIFT-like pipeline:
//   Sobel(3x3, pad1) -> project onto 8 orientations -> argmax -> magnitude
//   into winning bin -> depthwise 4x4 ones conv (pad2) => out (8,8,1025,1025)
//
// Tile: one wave (64 lanes) owns a 61-col x 32-row output tile.
// Lane l owns hist column (j0-2+l). Output col c needs hist cols c..c+3
// => horizontal 4-tap sum via __shfl_down pair tree; lanes 61..63 feed only.
// Vertical: 8 groups of 4 output rows; group g consumes hist rows 4g..4g+6,
// each hist pixel is Sobel'd + channel-expanded ONCE (static slot indices).

#define TW 61      // output cols per tile
#define TH 32      // output rows per tile
#define XC 66      // staged x cols  (j0-3 .. j0+62)
#define XR 37      // staged x rows  (i0-3 .. i0+33)

__global__ __launch_bounds__(64, 4)
void sift_fused(const float* __restrict__ x,
                const float* __restrict__ ow,
                float* __restrict__ out)
{
    __shared__ float sx[XR * XC];

    const int lane = threadIdx.x;
    const int j0 = blockIdx.x * TW;
    const int i0 = blockIdx.y * TH;
    const int b  = blockIdx.z;

    // ---- stage x tile into LDS (zero-padded at image borders) ----
    const float* xb_ptr = x + (size_t)b * 1024 * 1024;
    for (int p = lane; p < XR * XC; p += 64) {
        int r = p / XC, c = p - r * XC;
        int gr = i0 - 3 + r, gc = j0 - 3 + c;
        float v = 0.0f;
        if ((unsigned)gr < 1024u && (unsigned)gc < 1024u)
            v = xb_ptr[(size_t)gr * 1024 + gc];
        sx[p] = v;
    }
    __syncthreads();

    // ---- orientation weights (read from input => bit-exact vs reference) ----
    float wc[8], ws[8];
    #pragma unroll
    for (int o = 0; o < 8; ++o) { wc[o] = ow[2 * o]; ws[o] = ow[2 * o + 1]; }

    const int gcol = j0 - 2 + lane;            // hist column this lane owns
    const bool colok = (unsigned)gcol < 1024u;
    const int gj = j0 + lane;                  // output column this lane stores
    const bool canstore = (lane < TW) && (gj <= 1024);

    for (int g = 0; g < 8; ++g) {
        const int r0 = i0 + 4 * g;             // first output row of this group
        if (r0 > 1024) break;                  // uniform across wave

        float cs[4][8];
        #pragma unroll
        for (int k = 0; k < 4; ++k) {
            #pragma unroll
            for (int o = 0; o < 8; ++o) cs[k][o] = 0.0f;
        }

        // x register window over local rows 4g .. 4g+8 (3 cols per lane)
        const int xbase = 4 * g;
        float a0 = sx[(xbase + 0) * XC + lane];
        float a1 = sx[(xbase + 0) * XC + lane + 1];
        float a2 = sx[(xbase + 0) * XC + lane + 2];
        float b0 = sx[(xbase + 1) * XC + lane];
        float b1 = sx[(xbase + 1) * XC + lane + 1];
        float b2 = sx[(xbase + 1) * XC + lane + 2];

        #pragma unroll
        for (int j = 0; j < 7; ++j) {
            float c0 = sx[(xbase + j + 2) * XC + lane];
            float c1 = sx[(xbase + j + 2) * XC + lane + 1];
            float c2 = sx[(xbase + j + 2) * XC + lane + 2];

            // Sobel (cross-correlation, matches jax.lax.conv)
            float gx = (a2 - a0) + 2.0f * (b2 - b0) + (c2 - c0);
            float gy = (c0 + 2.0f * c1 + c2) - (a0 + 2.0f * a1 + a2);

            const int grow = i0 - 2 + 4 * g + j;   // global hist row
            float m = (colok && (unsigned)grow < 1024u)
                        ? sqrtf(gx * gx + gy * gy) : 0.0f;

            // argmax over 8 orientation projections (first-max wins)
            float best = gx * wc[0] + gy * ws[0];
            int idx = 0;
            #pragma unroll
            for (int o = 1; o < 8; ++o) {
                float co = gx * wc[o] + gy * ws[o];
                if (co > best) { best = co; idx = o; }
            }

            float contrib[8];
            #pragma unroll
            for (int o = 0; o < 8; ++o)
                contrib[o] = (idx == o) ? m : 0.0f;

            // hist row (in-group j) feeds output rows k with k <= j <= k+3
            #pragma unroll
            for (int k = 0; k < 4; ++k) {
                if (k <= j && j <= k + 3) {
                    #pragma unroll
                    for (int o = 0; o < 8; ++o)
                        cs[k][o] += contrib[o];
                }
            }

            a0 = b0; a1 = b1; a2 = b2;
            b0 = c0; b1 = c1; b2 = c2;
        }

        // horizontal 4-tap sum across lanes + store
        #pragma unroll
        for (int k = 0; k < 4; ++k) {
            const int grow_out = r0 + k;
            const bool ok = canstore && (grow_out <= 1024);
            #pragma unroll
            for (int o = 0; o < 8; ++o) {
                float v = cs[k][o];
                v += __shfl_down(v, 1);
                v += __shfl_down(v, 2);
                if (ok) {
                    size_t oi = ((size_t)(b * 8 + o) * 1025 + grow_out) * 1025 + gj;
                    out[oi] = v;
                }
            }
        }
    }
}

extern "C" void kernel_launch(void* const* d_in, const int* in_sizes, int n_in,
                              void* d_out, int out_size, void* d_ws, size_t ws_size,
                              hipStream_t stream)
{
    const float* x  = (const float*)d_in[0];
    const float* ow = (const float*)d_in[2];   // orient_w (10,2): rows 0..7 = [cos, sin]
    float* out = (float*)d_out;

    dim3 grid((1025 + TW - 1) / TW,   // 17 col tiles
              (1025 + TH - 1) / TH,   // 33 row tiles
              8);                     // batch
    sift_fused<<<grid, 64, 0, stream>>>(x, ow, out);
}

// Round 2
// 101.809 us; speedup vs baseline: 1.2532x; 1.2532x over previous
//
#include <hip/hip_runtime.h>
#include <math.h>

// Fused SIFT-like pipeline:
//   Sobel(3x3, pad1) -> project onto 8 orientations -> argmax -> magnitude
//   into winning bin -> depthwise 4x4 ones conv (pad2) => out (8,8,1025,1025)
//
// v2: rolling-ring accumulator (each hist row computed ONCE), 4-wave blocks
// sharing one LDS tile for occupancy (32-wave/CU LDS budget).
//
// Block = 256 threads (4 waves). Block tile: 61 out cols x 64 out rows.
// Wave wv owns 16 out rows. Lane l owns hist column j0-2+l; out col c needs
// hist cols c..c+3 => 4-tap via __shfl_down pair tree (lanes 61..63 feed only).
// Vertically: 19 hist rows per wave walked once; a 4-deep ring of 8-channel
// accumulators (static slot indices via full unroll) receives each hist pixel;
// out row t is finalized right after hist row t+3.

#define WPB 4               // waves per block
#define TWC 61              // out cols per tile
#define WTH 16              // out rows per wave
#define BTH (WPB*WTH)       // 64 out rows per block
#define XC 66               // staged x cols (j0-3 .. j0+62)
#define XR (BTH+5)          // 69 staged x rows (r0-3 .. r0+65)

__global__ __launch_bounds__(256, 4)
void sift_fused(const float* __restrict__ x,
                const float* __restrict__ ow,
                float* __restrict__ out)
{
    __shared__ float sx[XR * XC];

    const int tid  = threadIdx.x;
    const int lane = tid & 63;
    const int wv   = tid >> 6;
    const int j0 = blockIdx.x * TWC;
    const int r0 = blockIdx.y * BTH;
    const int bb = blockIdx.z;

    // ---- stage x tile into LDS (zero-padded at image borders) ----
    const float* xb = x + (size_t)bb * 1024 * 1024;
    for (int p = tid; p < XR * XC; p += 256) {
        int r = p / XC, c = p - r * XC;
        int gr = r0 - 3 + r, gc = j0 - 3 + c;
        float v = 0.0f;
        if ((unsigned)gr < 1024u && (unsigned)gc < 1024u)
            v = xb[(size_t)gr * 1024 + gc];
        sx[p] = v;
    }
    __syncthreads();

    // orientation weights from input => bit-exact argmax vs reference
    float wcn[8], wsn[8];
    #pragma unroll
    for (int o = 0; o < 8; ++o) { wcn[o] = ow[2*o]; wsn[o] = ow[2*o+1]; }

    const int gcol = j0 - 2 + lane;              // hist column this lane owns
    const bool colok = (unsigned)gcol < 1024u;
    const int gj = j0 + lane;                    // output column this lane stores
    const bool canstore = (lane < TWC) && (gj <= 1024);
    const int rbase = r0 + WTH * wv;             // first output row of this wave
    const int hbase = rbase - 2;                 // global hist row at j=0
    const float* sxw = sx + (WTH * wv) * XC + lane;
    float* outb = out + (size_t)bb * 8u * 1025u * 1025u + gj;

    float cs0[8], cs1[8], cs2[8], cs3[8];
    #pragma unroll
    for (int o = 0; o < 8; ++o) { cs0[o]=0.f; cs1[o]=0.f; cs2[o]=0.f; cs3[o]=0.f; }

    // 3-row x window registers (top a*, mid e*)
    float a0 = sxw[0],  a1 = sxw[1],    a2 = sxw[2];
    float e0 = sxw[XC], e1 = sxw[XC+1], e2 = sxw[XC+2];

// hist row J: load bottom row, Sobel, argmax, magnitude; add one-hot contrib
// into ring slots CT0..CT3 (for out rows t=J, J-1, J-2, J-3) gated by
// compile-time flags D0..D3; then shift the x window.
#define HROW(J, D0,CT0, D1,CT1, D2,CT2, D3,CT3) { \
    float n0 = sxw[((J)+2)*XC], n1 = sxw[((J)+2)*XC+1], n2 = sxw[((J)+2)*XC+2]; \
    float gx = (a2 - a0) + 2.0f*(e2 - e0) + (n2 - n0); \
    float gy = (n0 + 2.0f*n1 + n2) - (a0 + 2.0f*a1 + a2); \
    int hrow = hbase + (J); \
    float m = (colok && (unsigned)hrow < 1024u) ? sqrtf(gx*gx + gy*gy) : 0.0f; \
    float best = gx*wcn[0] + gy*wsn[0]; int idx = 0; \
    _Pragma("unroll") \
    for (int o = 1; o < 8; ++o) { \
        float co = gx*wcn[o] + gy*wsn[o]; \
        if (co > best) { best = co; idx = o; } \
    } \
    _Pragma("unroll") \
    for (int o = 0; o < 8; ++o) { \
        float cb = (idx == o) ? m : 0.0f; \
        if (D0) CT0[o] += cb; \
        if (D1) CT1[o] += cb; \
        if (D2) CT2[o] += cb; \
        if (D3) CT3[o] += cb; \
    } \
    a0 = e0; a1 = e1; a2 = e2; e0 = n0; e1 = n1; e2 = n2; \
}

// finalize out row T from ring slot CS: 4-tap horizontal sum + store, reset CS
#define FIN(T, CS) { \
    int orow = rbase + (T); \
    bool ok = canstore && (orow <= 1024); \
    _Pragma("unroll") \
    for (int o = 0; o < 8; ++o) { \
        float v = CS[o]; \
        v += __shfl_down(v, 1); \
        v += __shfl_down(v, 2); \
        if (ok) outb[(size_t)o * (1025u*1025u) + (size_t)orow * 1025u] = v; \
        CS[o] = 0.0f; \
    } \
}

#define QUAD(J) \
    HROW((J),   1,cs0, 1,cs3, 1,cs2, 1,cs1) FIN((J)-3, cs1) \
    HROW((J)+1, 1,cs1, 1,cs0, 1,cs3, 1,cs2) FIN((J)-2, cs2) \
    HROW((J)+2, 1,cs2, 1,cs1, 1,cs0, 1,cs3) FIN((J)-1, cs3) \
    HROW((J)+3, 1,cs3, 1,cs2, 1,cs1, 1,cs0) FIN((J),   cs0)

    // prologue: t = j-3.. not yet valid
    HROW(0, 1,cs0, 0,cs0, 0,cs0, 0,cs0)
    HROW(1, 1,cs1, 1,cs0, 0,cs0, 0,cs0)
    HROW(2, 1,cs2, 1,cs1, 1,cs0, 0,cs0)
    HROW(3, 1,cs3, 1,cs2, 1,cs1, 1,cs0) FIN(0, cs0)
    // steady state
    QUAD(4) QUAD(8) QUAD(12)
    // epilogue: t = j no longer valid
    HROW(16, 0,cs0, 1,cs3, 1,cs2, 1,cs1) FIN(13, cs1)
    HROW(17, 0,cs0, 0,cs0, 1,cs3, 1,cs2) FIN(14, cs2)
    HROW(18, 0,cs0, 0,cs0, 0,cs0, 1,cs3) FIN(15, cs3)

#undef QUAD
#undef FIN
#undef HROW
}

extern "C" void kernel_launch(void* const* d_in, const int* in_sizes, int n_in,
                              void* d_out, int out_size, void* d_ws, size_t ws_size,
                              hipStream_t stream)
{
    const float* x  = (const float*)d_in[0];
    const float* ow = (const float*)d_in[2];   // orient_w (10,2): rows 0..7 = [cos, sin]
    float* out = (float*)d_out;

    dim3 grid((1025 + TWC - 1) / TWC,   // 17 col tiles
              (1025 + BTH - 1) / BTH,   // 17 row tiles (64 rows/block)
              8);                       // batch
    sift_fused<<<grid, 256, 0, stream>>>(x, ow, out);
}

// Round 3
// 101.177 us; speedup vs baseline: 1.2610x; 1.0062x over previous
//
#include <hip/hip_runtime.h>
#include <math.h>

// Fused SIFT-like pipeline:
//   Sobel(3x3, pad1) -> project onto 8 orientations -> argmax -> magnitude
//   into winning bin -> depthwise 4x4 ones conv (pad2) => out (8,8,1025,1025)
//
// v3: rolled QUAD loop (small I$), tournament argmax (depth 3, exact same
// semantics), pair-sum vertical window (P_j = c_{j-1}+c_j), d/w row-sum
// reuse (bit-identical gx/gy trees vs v2), fast sqrt, SGPR-base stores,
// launch_bounds(256,5) for occupancy.
//
// Block = 256 threads (4 waves), tile 61 out cols x 64 out rows; wave owns
// 16 rows. Lane l owns hist col j0-2+l; out col c = hist cols c..c+3 via
// __shfl_down pair tree (lanes 61..63 feed only).

#define TWC 61              // out cols per tile
#define WTH 16              // out rows per wave
#define WPB 4               // waves per block
#define BTH (WPB*WTH)       // 64 out rows per block
#define XC 66               // staged x cols (j0-3 .. j0+62)
#define XR (BTH+5)          // 69 staged x rows
#define PLANE 1050625       // 1025*1025

__global__ __launch_bounds__(256, 5)
void sift_fused(const float* __restrict__ x,
                const float* __restrict__ ow,
                float* __restrict__ out)
{
    __shared__ float sx[XR * XC];

    const int tid  = threadIdx.x;
    const int lane = tid & 63;
    const int wv   = tid >> 6;
    const int j0 = blockIdx.x * TWC;
    const int r0 = blockIdx.y * BTH;
    const int bb = blockIdx.z;

    // ---- stage x tile into LDS (zero-padded at image borders) ----
    const float* xb = x + (size_t)bb * 1024 * 1024;
    for (int p = tid; p < XR * XC; p += 256) {
        int r = p / XC, c = p - r * XC;
        int gr = r0 - 3 + r, gc = j0 - 3 + c;
        float v = 0.0f;
        if ((unsigned)gr < 1024u && (unsigned)gc < 1024u)
            v = xb[(size_t)gr * 1024 + gc];
        sx[p] = v;
    }
    __syncthreads();

    const int rbase = r0 + WTH * wv;           // first output row of this wave
    if (rbase > 1024) return;                  // no barriers after this point

    // orientation weights (uniform loads -> SGPR)
    float wcn[8], wsn[8];
    #pragma unroll
    for (int o = 0; o < 8; ++o) { wcn[o] = ow[2*o]; wsn[o] = ow[2*o+1]; }

    const int gcol = j0 - 2 + lane;            // hist column this lane owns
    const bool colok = (unsigned)gcol < 1024u;
    const int gj = j0 + lane;                  // output column this lane stores
    const bool canstore = (lane < TWC) && (gj <= 1024);

    // 8 uniform per-channel plane base pointers (SGPR pairs)
    float* po[8];
    #pragma unroll
    for (int o = 0; o < 8; ++o) po[o] = out + (size_t)(bb * 8 + o) * PLANE;

    const float* px = sx + (WTH * wv) * XC + lane;  // x row cursor (3 cols/lane)
    int hrow = rbase - 2;                      // global hist row of current step
    int orow = rbase;                          // global out row of next FIN
    int vo   = rbase * 1025 + gj;              // element offset within a plane

    // register state: d/w row-sum rings (slot = xrow & 3), contrib ping-pong,
    // pair-sum ring (slot = histrow & 3)
    float dd0, dd1, dd2, dd3, ww0, ww1, ww2, ww3;
    float cA[8], cB[8], PP0[8], PP1[8], PP2[8], PP3[8];

#define XROWLOAD(DD, WW) { \
    float n0 = px[0], n1 = px[1], n2 = px[2]; px += XC; \
    DD = n2 - n0; \
    WW = n0 + 2.0f*n1 + n2; \
}

// One hist row: load x row j+2 -> (DB,WB); Sobel from rings (bit-identical
// trees to v2); magnitude; tournament argmax (== sequential first-max);
// one-hot contrib CC; pair sum PC = CP + CC; optional FIN of out row j-3.
#define HSTEP(DT, DM, DB, WT, WB, CP, CC, PR, PC, DOP, DOFIN) { \
    XROWLOAD(DB, WB) \
    float gx = DT + 2.0f*DM + DB; \
    float gy = WB - WT; \
    float msq = gx*gx + gy*gy; \
    float m = (colok && (unsigned)hrow < 1024u) \
                ? __builtin_amdgcn_sqrtf(msq) : 0.0f; \
    hrow++; \
    float pj0 = gx*wcn[0] + gy*wsn[0]; \
    float pj1 = gx*wcn[1] + gy*wsn[1]; \
    float pj2 = gx*wcn[2] + gy*wsn[2]; \
    float pj3 = gx*wcn[3] + gy*wsn[3]; \
    float pj4 = gx*wcn[4] + gy*wsn[4]; \
    float pj5 = gx*wcn[5] + gy*wsn[5]; \
    float pj6 = gx*wcn[6] + gy*wsn[6]; \
    float pj7 = gx*wcn[7] + gy*wsn[7]; \
    bool g01 = pj1 > pj0; float b01 = g01 ? pj1 : pj0; int i01 = g01 ? 1 : 0; \
    bool g23 = pj3 > pj2; float b23 = g23 ? pj3 : pj2; int i23 = g23 ? 3 : 2; \
    bool g45 = pj5 > pj4; float b45 = g45 ? pj5 : pj4; int i45 = g45 ? 5 : 4; \
    bool g67 = pj7 > pj6; float b67 = g67 ? pj7 : pj6; int i67 = g67 ? 7 : 6; \
    bool gA = b23 > b01; float bA = gA ? b23 : b01; int iA = gA ? i23 : i01; \
    bool gB = b67 > b45; float bB = gB ? b67 : b45; int iB = gB ? i67 : i45; \
    int idx = (bB > bA) ? iB : iA; \
    _Pragma("unroll") \
    for (int o = 0; o < 8; ++o) CC[o] = (idx == o) ? m : 0.0f; \
    if (DOP) { \
        _Pragma("unroll") \
        for (int o = 0; o < 8; ++o) PC[o] = CP[o] + CC[o]; \
    } \
    if (DOFIN) { \
        bool ok = canstore && (orow <= 1024); \
        _Pragma("unroll") \
        for (int o = 0; o < 8; ++o) { \
            float v = PR[o] + PC[o]; \
            v += __shfl_down(v, 1); \
            v += __shfl_down(v, 2); \
            if (ok) po[o][vo] = v; \
        } \
        vo += 1025; orow++; \
    } \
}

    // prologue: x rows 0,1 then hist rows j=0..2 (no FIN yet)
    XROWLOAD(dd0, ww0)
    XROWLOAD(dd1, ww1)
    HSTEP(dd0, dd1, dd2, ww0, ww2, cA, cB, PP0, PP0, 0, 0)   // j=0 (P_0 unused)
    HSTEP(dd1, dd2, dd3, ww1, ww3, cB, cA, PP0, PP1, 1, 0)   // j=1
    HSTEP(dd2, dd3, dd0, ww2, ww0, cA, cB, PP0, PP2, 1, 0)   // j=2

    // steady state: j = 3..18, FIN t = j-3 = 0..15
    #pragma unroll 1
    for (int it = 0; it < 4; ++it) {
        HSTEP(dd3, dd0, dd1, ww3, ww1, cB, cA, PP1, PP3, 1, 1)   // j%4==3
        HSTEP(dd0, dd1, dd2, ww0, ww2, cA, cB, PP2, PP0, 1, 1)   // j%4==0
        HSTEP(dd1, dd2, dd3, ww1, ww3, cB, cA, PP3, PP1, 1, 1)   // j%4==1
        HSTEP(dd2, dd3, dd0, ww2, ww0, cA, cB, PP0, PP2, 1, 1)   // j%4==2
    }

#undef HSTEP
#undef XROWLOAD
}

extern "C" void kernel_launch(void* const* d_in, const int* in_sizes, int n_in,
                              void* d_out, int out_size, void* d_ws, size_t ws_size,
                              hipStream_t stream)
{
    const float* x  = (const float*)d_in[0];
    const float* ow = (const float*)d_in[2];   // orient_w (10,2): rows 0..7 = [cos, sin]
    float* out = (float*)d_out;

    dim3 grid((1025 + TWC - 1) / TWC,   // 17 col tiles
              (1025 + BTH - 1) / BTH,   // 17 row tiles
              8);                       // batch
    sift_fused<<<grid, 256, 0, stream>>>(x, ow, out);
}

// Round 4
// 90.253 us; speedup vs baseline: 1.4136x; 1.1210x over previous
//
#include <hip/hip_runtime.h>
#include <math.h>

// Fused SIFT-like pipeline:
//   Sobel(3x3, pad1) -> project onto 8 orientations -> argmax -> magnitude
//   into winning bin -> depthwise 4x4 ones conv (pad2) => out (8,8,1025,1025)
//
// v4 = v3 + XCD-aware block swizzle: batch == XCD (8 batches, 8 XCDs).
// Theory: 61-float (244B) store chunks partially cover edge 128B lines;
// adjacent chunks come from adjacent blocks which round-robin across XCDs,
// so boundary lines are dirty in two non-coherent L2s -> RMW below L2.
// Mapping each batch's entire output (8 planes) to ONE XCD lets its L2
// merge all partials into full lines. Perf-only assumption; bijective remap.
//
// Block = 256 threads (4 waves), tile 61 out cols x 64 out rows; wave owns
// 16 rows. Lane l owns hist col j0-2+l; out col c = hist cols c..c+3 via
// __shfl_down pair tree (lanes 61..63 feed only).

#define TWC 61              // out cols per tile
#define WTH 16              // out rows per wave
#define WPB 4               // waves per block
#define BTH (WPB*WTH)       // 64 out rows per block
#define XC 66               // staged x cols (j0-3 .. j0+62)
#define XR (BTH+5)          // 69 staged x rows
#define PLANE 1050625       // 1025*1025
#define NCT 17              // col tiles
#define NRT 17              // row tiles

__global__ __launch_bounds__(256, 5)
void sift_fused(const float* __restrict__ x,
                const float* __restrict__ ow,
                float* __restrict__ out)
{
    __shared__ float sx[XR * XC];

    const int tid  = threadIdx.x;
    const int lane = tid & 63;
    const int wv   = tid >> 6;

    // ---- XCD-aware remap: hardware round-robins flat id % 8 across XCDs.
    // Make batch = flat % 8 so each XCD owns one batch's planes entirely.
    const int flat = blockIdx.x + NCT * (blockIdx.y + NRT * blockIdx.z);
    const int bb = flat & 7;            // batch  == XCD
    const int t  = flat >> 3;           // 0 .. 288
    const int bx = t % NCT;
    const int by = t / NCT;

    const int j0 = bx * TWC;
    const int r0 = by * BTH;

    // ---- stage x tile into LDS (zero-padded at image borders) ----
    const float* xb = x + (size_t)bb * 1024 * 1024;
    for (int p = tid; p < XR * XC; p += 256) {
        int r = p / XC, c = p - r * XC;
        int gr = r0 - 3 + r, gc = j0 - 3 + c;
        float v = 0.0f;
        if ((unsigned)gr < 1024u && (unsigned)gc < 1024u)
            v = xb[(size_t)gr * 1024 + gc];
        sx[p] = v;
    }
    __syncthreads();

    const int rbase = r0 + WTH * wv;           // first output row of this wave
    if (rbase > 1024) return;                  // no barriers after this point

    // orientation weights (uniform loads -> SGPR)
    float wcn[8], wsn[8];
    #pragma unroll
    for (int o = 0; o < 8; ++o) { wcn[o] = ow[2*o]; wsn[o] = ow[2*o+1]; }

    const int gcol = j0 - 2 + lane;            // hist column this lane owns
    const bool colok = (unsigned)gcol < 1024u;
    const int gj = j0 + lane;                  // output column this lane stores
    const bool canstore = (lane < TWC) && (gj <= 1024);

    // 8 uniform per-channel plane base pointers (SGPR pairs)
    float* po[8];
    #pragma unroll
    for (int o = 0; o < 8; ++o) po[o] = out + (size_t)(bb * 8 + o) * PLANE;

    const float* px = sx + (WTH * wv) * XC + lane;  // x row cursor (3 cols/lane)
    int hrow = rbase - 2;                      // global hist row of current step
    int orow = rbase;                          // global out row of next FIN
    int vo   = rbase * 1025 + gj;              // element offset within a plane

    // register state: d/w row-sum rings (slot = xrow & 3), contrib ping-pong,
    // pair-sum ring (slot = histrow & 3)
    float dd0, dd1, dd2, dd3, ww0, ww1, ww2, ww3;
    float cA[8], cB[8], PP0[8], PP1[8], PP2[8], PP3[8];

#define XROWLOAD(DD, WW) { \
    float n0 = px[0], n1 = px[1], n2 = px[2]; px += XC; \
    DD = n2 - n0; \
    WW = n0 + 2.0f*n1 + n2; \
}

// One hist row: load x row j+2 -> (DB,WB); Sobel from rings; magnitude;
// tournament argmax (== sequential first-max); one-hot contrib CC;
// pair sum PC = CP + CC; optional FIN of out row j-3.
#define HSTEP(DT, DM, DB, WT, WB, CP, CC, PR, PC, DOP, DOFIN) { \
    XROWLOAD(DB, WB) \
    float gx = DT + 2.0f*DM + DB; \
    float gy = WB - WT; \
    float msq = gx*gx + gy*gy; \
    float m = (colok && (unsigned)hrow < 1024u) \
                ? __builtin_amdgcn_sqrtf(msq) : 0.0f; \
    hrow++; \
    float pj0 = gx*wcn[0] + gy*wsn[0]; \
    float pj1 = gx*wcn[1] + gy*wsn[1]; \
    float pj2 = gx*wcn[2] + gy*wsn[2]; \
    float pj3 = gx*wcn[3] + gy*wsn[3]; \
    float pj4 = gx*wcn[4] + gy*wsn[4]; \
    float pj5 = gx*wcn[5] + gy*wsn[5]; \
    float pj6 = gx*wcn[6] + gy*wsn[6]; \
    float pj7 = gx*wcn[7] + gy*wsn[7]; \
    bool g01 = pj1 > pj0; float b01 = g01 ? pj1 : pj0; int i01 = g01 ? 1 : 0; \
    bool g23 = pj3 > pj2; float b23 = g23 ? pj3 : pj2; int i23 = g23 ? 3 : 2; \
    bool g45 = pj5 > pj4; float b45 = g45 ? pj5 : pj4; int i45 = g45 ? 5 : 4; \
    bool g67 = pj7 > pj6; float b67 = g67 ? pj7 : pj6; int i67 = g67 ? 7 : 6; \
    bool gA = b23 > b01; float bA = gA ? b23 : b01; int iA = gA ? i23 : i01; \
    bool gB = b67 > b45; float bB = gB ? b67 : b45; int iB = gB ? i67 : i45; \
    int idx = (bB > bA) ? iB : iA; \
    _Pragma("unroll") \
    for (int o = 0; o < 8; ++o) CC[o] = (idx == o) ? m : 0.0f; \
    if (DOP) { \
        _Pragma("unroll") \
        for (int o = 0; o < 8; ++o) PC[o] = CP[o] + CC[o]; \
    } \
    if (DOFIN) { \
        bool ok = canstore && (orow <= 1024); \
        _Pragma("unroll") \
        for (int o = 0; o < 8; ++o) { \
            float v = PR[o] + PC[o]; \
            v += __shfl_down(v, 1); \
            v += __shfl_down(v, 2); \
            if (ok) po[o][vo] = v; \
        } \
        vo += 1025; orow++; \
    } \
}

    // prologue: x rows 0,1 then hist rows j=0..2 (no FIN yet)
    XROWLOAD(dd0, ww0)
    XROWLOAD(dd1, ww1)
    HSTEP(dd0, dd1, dd2, ww0, ww2, cA, cB, PP0, PP0, 0, 0)   // j=0 (P_0 unused)
    HSTEP(dd1, dd2, dd3, ww1, ww3, cB, cA, PP0, PP1, 1, 0)   // j=1
    HSTEP(dd2, dd3, dd0, ww2, ww0, cA, cB, PP0, PP2, 1, 0)   // j=2

    // steady state: j = 3..18, FIN t = j-3 = 0..15
    #pragma unroll 1
    for (int it = 0; it < 4; ++it) {
        HSTEP(dd3, dd0, dd1, ww3, ww1, cB, cA, PP1, PP3, 1, 1)   // j%4==3
        HSTEP(dd0, dd1, dd2, ww0, ww2, cA, cB, PP2, PP0, 1, 1)   // j%4==0
        HSTEP(dd1, dd2, dd3, ww1, ww3, cB, cA, PP3, PP1, 1, 1)   // j%4==1
        HSTEP(dd2, dd3, dd0, ww2, ww0, cA, cB, PP0, PP2, 1, 1)   // j%4==2
    }

#undef HSTEP
#undef XROWLOAD
}

extern "C" void kernel_launch(void* const* d_in, const int* in_sizes, int n_in,
                              void* d_out, int out_size, void* d_ws, size_t ws_size,
                              hipStream_t stream)
{
    const float* x  = (const float*)d_in[0];
    const float* ow = (const float*)d_in[2];   // orient_w (10,2): rows 0..7 = [cos, sin]
    float* out = (float*)d_out;

    dim3 grid(NCT,    // col tiles (remapped inside kernel)
              NRT,    // row tiles
              8);     // batch
    sift_fused<<<grid, 256, 0, stream>>>(x, ow, out);
}